// Round 1
// baseline (68558.661 us; speedup 1.0000x reference)
//
#include <hip/hip_runtime.h>
#include <math.h>

// TemporalPredictionNetwork: L=4 levels, S=512 steps, H=1024, B=1.
// Wavefront-parallel persistent kernel: diagonal cells (t = r - lvl) run
// concurrently; 5 grid-barrier phases per round; 515 rounds.
#define NLVL 4
#define HDIM 1024
#define SEQ  512
#define THREADS 512                 // 8 waves per workgroup
#define WGS_PER_LVL 64
#define NWG (NLVL * WGS_PER_LVL)    // 256 workgroups (1 per CU)
#define NWAVES (THREADS / 64)
#define SLICE_WAVES (WGS_PER_LVL * NWAVES)   // 512 waves per level slice

// workspace layout (float offsets)
#define WS_HS    0                      // [2][NLVL][HDIM] double-buffered hidden
#define WS_T1    (WS_HS + 2*NLVL*HDIM)  // [NLVL][HDIM]
#define WS_ERR   (WS_T1 + NLVL*HDIM)
#define WS_T2    (WS_ERR + NLVL*HDIM)
#define WS_ENC   (WS_T2 + NLVL*HDIM)
#define WS_CTRL  (WS_ENC + NLVL*HDIM)   // dprec[4], fepart[4], sync[2]

__device__ __forceinline__ float gelu_f(float x) {
  return 0.5f * x * (1.0f + erff(x * 0.70710678118654752f));
}
__device__ __forceinline__ float sigmoid_f(float x) {
  return 1.0f / (1.0f + __expf(-x));
}

__device__ __forceinline__ float wredux(float v) {
#pragma unroll
  for (int off = 32; off > 0; off >>= 1) v += __shfl_down(v, off, 64);
  return v;  // valid in lane 0
}

// dot( W_row[0:1024], x_lds[0:1024] ) across one wave; result in lane 0
__device__ __forceinline__ float dot_row(const float* __restrict__ w,
                                         const float* __restrict__ xl, int lane) {
  const float4* __restrict__ w4 = (const float4*)w;
  const float4* __restrict__ x4 = (const float4*)xl;
  float acc = 0.f;
#pragma unroll
  for (int i = 0; i < HDIM / 4; i += 64) {
    float4 a = w4[i + lane];
    float4 b = x4[i + lane];
    acc = fmaf(a.x, b.x, acc); acc = fmaf(a.y, b.y, acc);
    acc = fmaf(a.z, b.z, acc); acc = fmaf(a.w, b.w, acc);
  }
  return wredux(acc);
}

// sense-reversing grid barrier, agent scope
__device__ __forceinline__ void gbar(unsigned* syn) {
  __syncthreads();
  if (threadIdx.x == 0) {
    unsigned* cnt = syn;
    unsigned* gen = syn + 1;
    unsigned g = __hip_atomic_load(gen, __ATOMIC_RELAXED, __HIP_MEMORY_SCOPE_AGENT);
    unsigned v = __hip_atomic_fetch_add(cnt, 1u, __ATOMIC_ACQ_REL, __HIP_MEMORY_SCOPE_AGENT);
    if (v == NWG - 1u) {
      __hip_atomic_store(cnt, 0u, __ATOMIC_RELAXED, __HIP_MEMORY_SCOPE_AGENT);
      __hip_atomic_store(gen, g + 1u, __ATOMIC_RELEASE, __HIP_MEMORY_SCOPE_AGENT);
    } else {
      while (__hip_atomic_load(gen, __ATOMIC_RELAXED, __HIP_MEMORY_SCOPE_AGENT) == g)
        __builtin_amdgcn_s_sleep(1);
      (void)__hip_atomic_load(gen, __ATOMIC_ACQUIRE, __HIP_MEMORY_SCOPE_AGENT);
    }
  }
  __syncthreads();
}

extern "C" __global__ void tpn_init(float* ws) {
  int i = blockIdx.x * blockDim.x + threadIdx.x;
  int n = blockDim.x * gridDim.x;
  for (int k = i; k < 2 * NLVL * HDIM; k += n) ws[WS_HS + k] = 0.f;
  if (i < 16) ws[WS_CTRL + i] = 0.f;   // dprec, fepart, sync counters
}

extern "C" __global__ void __launch_bounds__(THREADS) tpn_main(
    const float* __restrict__ observed,
    const float* __restrict__ pw1, const float* __restrict__ pb1,
    const float* __restrict__ pw2, const float* __restrict__ pb2,
    const float* __restrict__ ew1, const float* __restrict__ eb1,
    const float* __restrict__ ew2, const float* __restrict__ eb2,
    const float* __restrict__ qw,  const float* __restrict__ qb,
    const float* __restrict__ wih, const float* __restrict__ bih,
    const float* __restrict__ bhh,
    float* __restrict__ out, float* __restrict__ ws)
{
  __shared__ __align__(16) float xl[HDIM];
  const int wg   = blockIdx.x;
  const int lvl  = wg / WGS_PER_LVL;
  const int wgl  = wg % WGS_PER_LVL;
  const int wave = threadIdx.x >> 6;
  const int lane = threadIdx.x & 63;
  const int swid = wgl * NWAVES + wave;     // wave id within level slice

  float* hsbuf = ws + WS_HS;
  float* t1b   = ws + WS_T1;
  float* errb  = ws + WS_ERR;
  float* t2b   = ws + WS_T2;
  float* encb  = ws + WS_ENC;
  float* dprec = ws + WS_CTRL;
  float* fept  = ws + WS_CTRL + 4;
  unsigned* syn = (unsigned*)(ws + WS_CTRL + 8);

  const float* Wp1 = pw1 + (size_t)lvl * HDIM * HDIM;
  const float* Wp2 = pw2 + (size_t)lvl * HDIM * HDIM;
  const float* We1 = ew1 + (size_t)lvl * HDIM * HDIM;
  const float* We2 = ew2 + (size_t)lvl * HDIM * HDIM;
  const float* Wih = wih + (size_t)lvl * 4 * HDIM * HDIM;
  const float* bp1 = pb1 + lvl * HDIM;
  const float* bp2 = pb2 + lvl * HDIM;
  const float* be1 = eb1 + lvl * HDIM;
  const float* be2 = eb2 + lvl * HDIM;
  const float* qwl = qw + lvl * HDIM;
  const float* bi  = bih + lvl * 4 * HDIM;
  const float* bh  = bhh + lvl * 4 * HDIM;

  for (int r = 0; r < SEQ + NLVL - 1; ++r) {
    const int t = r - lvl;
    const bool act = (t >= 0) && (t < SEQ);

    // ---- P1: t1 = gelu(pw1 @ newh[lvl-1] + pb1)  (lvl >= 1) ----
    if (act && lvl > 0) {
      const float* src = hsbuf + ((t + 1) & 1) * (NLVL * HDIM) + (lvl - 1) * HDIM;
      for (int i = threadIdx.x; i < HDIM; i += THREADS) xl[i] = src[i];
      __syncthreads();
      for (int row = swid; row < HDIM; row += SLICE_WAVES) {
        float d = dot_row(Wp1 + (size_t)row * HDIM, xl, lane);
        if (lane == 0) t1b[lvl * HDIM + row] = gelu_f(d + bp1[row]);
      }
    }
    gbar(syn);

    // ---- P2: pred = pw2 @ t1 + pb2 ; err = enc[lvl-1] - pred ----
    if (act) {
      if (lvl > 0) {
        const float* src = t1b + lvl * HDIM;
        for (int i = threadIdx.x; i < HDIM; i += THREADS) xl[i] = src[i];
        __syncthreads();
        const float* inp = encb + (lvl - 1) * HDIM;
        for (int row = swid; row < HDIM; row += SLICE_WAVES) {
          float d = dot_row(Wp2 + (size_t)row * HDIM, xl, lane);
          if (lane == 0) {
            float pred = d + bp2[row];
            errb[lvl * HDIM + row] = inp[row] - pred;
            if (t == SEQ - 1) out[lvl * HDIM + row] = pred;   // preds[-1][lvl]
          }
        }
      } else if (t == SEQ - 1) {
        // level-0 prediction is identically zero
        for (int i = wgl * THREADS + threadIdx.x; i < HDIM; i += WGS_PER_LVL * THREADS)
          out[i] = 0.f;
      }
    }
    gbar(syn);

    // ---- P3: t2 = gelu(ew1 @ err + eb1) ; dprec = qw . err + qb ----
    if (act) {
      const float* src = (lvl == 0) ? (observed + (size_t)t * HDIM)
                                    : (errb + lvl * HDIM);
      for (int i = threadIdx.x; i < HDIM; i += THREADS) xl[i] = src[i];
      __syncthreads();
      for (int row = swid; row < HDIM; row += SLICE_WAVES) {
        float d = dot_row(We1 + (size_t)row * HDIM, xl, lane);
        if (lane == 0) t2b[lvl * HDIM + row] = gelu_f(d + be1[row]);
      }
      if (wgl == 0 && wave == 0) {
        float d = dot_row(qwl, xl, lane);
        if (lane == 0) dprec[lvl] = d + qb[lvl];
      }
    }
    gbar(syn);

    // ---- P4: enc = ew2 @ t2 + eb2 ----
    if (act) {
      const float* src = t2b + lvl * HDIM;
      for (int i = threadIdx.x; i < HDIM; i += THREADS) xl[i] = src[i];
      __syncthreads();
      for (int row = swid; row < HDIM; row += SLICE_WAVES) {
        float d = dot_row(We2 + (size_t)row * HDIM, xl, lane);
        if (lane == 0) {
          float e = d + be2[row];
          encb[lvl * HDIM + row] = e;
          if (t == SEQ - 1) out[NLVL * HDIM + lvl * HDIM + row] = e;  // errs[-1][lvl]
        }
      }
    }
    gbar(syn);

    // ---- P5: LSTM cell on upd = hs + prec*enc ; f-gate dead (c0 = 0) ----
    if (act) {
      const float prec = sigmoid_f(dprec[lvl]);
      const float* hold = hsbuf + (t & 1) * (NLVL * HDIM) + lvl * HDIM;
      const float* el = encb + lvl * HDIM;
      for (int i = threadIdx.x; i < HDIM; i += THREADS)
        xl[i] = fmaf(prec, el[i], hold[i]);
      __syncthreads();
      float* hnew = hsbuf + ((t + 1) & 1) * (NLVL * HDIM) + lvl * HDIM;
      for (int j = swid; j < HDIM; j += SLICE_WAVES) {
        float di = dot_row(Wih + (size_t)j * HDIM, xl, lane);                 // i gate
        float dg = dot_row(Wih + (size_t)(2 * HDIM + j) * HDIM, xl, lane);    // g gate
        float dob = dot_row(Wih + (size_t)(3 * HDIM + j) * HDIM, xl, lane);   // o gate
        if (lane == 0) {
          float gi = sigmoid_f(di + bi[j] + bh[j]);
          float gg = tanhf(dg + bi[2 * HDIM + j] + bh[2 * HDIM + j]);
          float go = sigmoid_f(dob + bi[3 * HDIM + j] + bh[3 * HDIM + j]);
          hnew[j] = go * tanhf(gi * gg);
        }
      }
      if (wgl == 0 && wave == 0) {   // fe += prec * sum(enc^2), per-level accum
        float s = 0.f;
        for (int i = lane; i < HDIM; i += 64) { float v = el[i]; s = fmaf(v, v, s); }
        s = wredux(s);
        if (lane == 0) fept[lvl] += prec * s;
      }
    }
    gbar(syn);
  }

  if (wg == 0 && threadIdx.x == 0)
    out[2 * NLVL * HDIM] = fept[0] + fept[1] + fept[2] + fept[3];
}

extern "C" void kernel_launch(void* const* d_in, const int* in_sizes, int n_in,
                              void* d_out, int out_size, void* d_ws, size_t ws_size,
                              hipStream_t stream) {
  const float* observed = (const float*)d_in[0];
  const float* pw1 = (const float*)d_in[1];
  const float* pb1 = (const float*)d_in[2];
  const float* pw2 = (const float*)d_in[3];
  const float* pb2 = (const float*)d_in[4];
  const float* ew1 = (const float*)d_in[5];
  const float* eb1 = (const float*)d_in[6];
  const float* ew2 = (const float*)d_in[7];
  const float* eb2 = (const float*)d_in[8];
  const float* qw  = (const float*)d_in[9];
  const float* qb  = (const float*)d_in[10];
  const float* wih = (const float*)d_in[11];
  // d_in[12] = whh — unused: h0 == 0 per step, W_hh term vanishes
  const float* bih = (const float*)d_in[13];
  const float* bhh = (const float*)d_in[14];
  float* out = (float*)d_out;
  float* ws  = (float*)d_ws;

  hipLaunchKernelGGL(tpn_init, dim3(32), dim3(256), 0, stream, ws);

  void* args[] = { &observed, &pw1, &pb1, &pw2, &pb2, &ew1, &eb1, &ew2, &eb2,
                   &qw, &qb, &wih, &bih, &bhh, &out, &ws };
  hipLaunchCooperativeKernel((void*)tpn_main, dim3(NWG), dim3(THREADS),
                             args, 0, stream);
}

// Round 2
// 19992.470 us; speedup vs baseline: 3.4292x; 3.4292x over previous
//
#include <hip/hip_runtime.h>
#include <math.h>

// TemporalPredictionNetwork: L=4 levels, S=512 steps, H=1024, B=1.
// Wavefront-parallel persistent kernel: diagonal cells (t = r - lvl) run
// concurrently; 5 grid-barrier phases per round; 515 rounds.
//
// Round-2: fence-free synchronization. All cross-WG shared state (small
// vectors + barrier words) uses agent-scope RELAXED atomics (performed at
// L3 coherence point, no L2 writeback/invalidate), ordered by explicit
// `s_waitcnt vmcnt(0)` before barrier arrival. Weights use plain cached
// loads and stay hot in L2/L3 (round-1's ACQ_REL barrier emitted
// buffer_wbl2/buffer_inv 2560x/round -> 27.7 GB HBM refetch, 70 ms).
#define NLVL 4
#define HDIM 1024
#define SEQ  512
#define THREADS 512                 // 8 waves per workgroup
#define WGS_PER_LVL 64
#define NWG (NLVL * WGS_PER_LVL)    // 256 workgroups (1 per CU)
#define NWAVES (THREADS / 64)
#define SLICE_WAVES (WGS_PER_LVL * NWAVES)   // 512 waves per level slice

// workspace layout (float offsets)
#define WS_HS    0                      // [2][NLVL][HDIM] double-buffered hidden
#define WS_T1    (WS_HS + 2*NLVL*HDIM)  // [NLVL][HDIM]
#define WS_ERR   (WS_T1 + NLVL*HDIM)
#define WS_T2    (WS_ERR + NLVL*HDIM)
#define WS_ENC   (WS_T2 + NLVL*HDIM)
#define WS_CTRL  (WS_ENC + NLVL*HDIM)   // barrier tree + dprec + fept (64B-strided)
#define WS_CTRL_WORDS 512
// ctrl word offsets (x16 = 64B stride to avoid false sharing)
#define C_GCNT(g) ((g) * 16)            // 8 group counters
#define C_ROOT    128
#define C_GEN     144
#define C_DPREC(l) (160 + (l) * 16)
#define C_FEPT(l)  (256 + (l) * 16)

__device__ __forceinline__ float gelu_f(float x) {
  return 0.5f * x * (1.0f + erff(x * 0.70710678118654752f));
}
__device__ __forceinline__ float sigmoid_f(float x) {
  return 1.0f / (1.0f + __expf(-x));
}

// agent-scope relaxed (fence-free, L2-bypassing) load/store
__device__ __forceinline__ float gload(const float* p) {
  return __hip_atomic_load((float*)p, __ATOMIC_RELAXED, __HIP_MEMORY_SCOPE_AGENT);
}
__device__ __forceinline__ void gstore(float* p, float v) {
  __hip_atomic_store(p, v, __ATOMIC_RELAXED, __HIP_MEMORY_SCOPE_AGENT);
}

__device__ __forceinline__ float wredux(float v) {
#pragma unroll
  for (int off = 32; off > 0; off >>= 1) v += __shfl_down(v, off, 64);
  return v;  // valid in lane 0
}

// dot( W_row[0:1024], x_lds[0:1024] ) across one wave; result in lane 0
__device__ __forceinline__ float dot_row(const float* __restrict__ w,
                                         const float* __restrict__ xl, int lane) {
  const float4* __restrict__ w4 = (const float4*)w;
  const float4* __restrict__ x4 = (const float4*)xl;
  float acc = 0.f;
#pragma unroll
  for (int i = 0; i < HDIM / 4; i += 64) {
    float4 a = w4[i + lane];
    float4 b = x4[i + lane];
    acc = fmaf(a.x, b.x, acc); acc = fmaf(a.y, b.y, acc);
    acc = fmaf(a.z, b.z, acc); acc = fmaf(a.w, b.w, acc);
  }
  return wredux(acc);
}

// two rows of one matrix against shared x, fused for memory-level parallelism
__device__ __forceinline__ void dot2(const float* __restrict__ W, int r0, int r1,
                                     const float* __restrict__ xl, int lane,
                                     float& o0, float& o1) {
  const float4* __restrict__ x4 = (const float4*)xl;
  const float4* __restrict__ w0 = (const float4*)(W + (size_t)r0 * HDIM);
  const float4* __restrict__ w1 = (const float4*)(W + (size_t)r1 * HDIM);
  float a0 = 0.f, a1 = 0.f;
#pragma unroll
  for (int i = 0; i < HDIM / 4; i += 64) {
    float4 b = x4[i + lane];
    float4 p = w0[i + lane];
    float4 q = w1[i + lane];
    a0 = fmaf(p.x, b.x, fmaf(p.y, b.y, fmaf(p.z, b.z, fmaf(p.w, b.w, a0))));
    a1 = fmaf(q.x, b.x, fmaf(q.y, b.y, fmaf(q.z, b.z, fmaf(q.w, b.w, a1))));
  }
  o0 = wredux(a0);
  o1 = wredux(a1);
}

// Fence-free 2-level tree barrier: 8 groups x 32 WGs, monotonic counters.
// Every wave drains its own vmcnt before s_barrier, so thread0's arrival
// add publishes "all this WG's agent-scope stores are at L3".
__device__ __forceinline__ void gbar(unsigned* ctrl, unsigned k, int wg) {
  asm volatile("s_waitcnt vmcnt(0)" ::: "memory");
  __syncthreads();
  if (threadIdx.x == 0) {
    unsigned* gcnt = ctrl + C_GCNT(wg >> 5);
    unsigned* root = ctrl + C_ROOT;
    unsigned* gen  = ctrl + C_GEN;
    unsigned old = __hip_atomic_fetch_add(gcnt, 1u, __ATOMIC_RELAXED,
                                          __HIP_MEMORY_SCOPE_AGENT);
    if (old == 32u * k - 1u) {
      unsigned o2 = __hip_atomic_fetch_add(root, 1u, __ATOMIC_RELAXED,
                                           __HIP_MEMORY_SCOPE_AGENT);
      if (o2 == 8u * k - 1u)
        __hip_atomic_store(gen, k, __ATOMIC_RELAXED, __HIP_MEMORY_SCOPE_AGENT);
    }
    while (__hip_atomic_load(gen, __ATOMIC_RELAXED, __HIP_MEMORY_SCOPE_AGENT) < k)
      __builtin_amdgcn_s_sleep(2);
  }
  __syncthreads();
}

extern "C" __global__ void tpn_init(float* ws) {
  int i = blockIdx.x * blockDim.x + threadIdx.x;
  int n = blockDim.x * gridDim.x;
  for (int k = i; k < 2 * NLVL * HDIM; k += n) ws[WS_HS + k] = 0.f;
  for (int k = i; k < WS_CTRL_WORDS; k += n) ws[WS_CTRL + k] = 0.f;
}

extern "C" __global__ void __launch_bounds__(THREADS) tpn_main(
    const float* __restrict__ observed,
    const float* __restrict__ pw1, const float* __restrict__ pb1,
    const float* __restrict__ pw2, const float* __restrict__ pb2,
    const float* __restrict__ ew1, const float* __restrict__ eb1,
    const float* __restrict__ ew2, const float* __restrict__ eb2,
    const float* __restrict__ qw,  const float* __restrict__ qb,
    const float* __restrict__ wih, const float* __restrict__ bih,
    const float* __restrict__ bhh,
    float* __restrict__ out, float* __restrict__ ws)
{
  __shared__ __align__(16) float xl[HDIM];
  __shared__ float s_prec;
  const int wg   = blockIdx.x;
  const int lvl  = wg / WGS_PER_LVL;
  const int wgl  = wg % WGS_PER_LVL;
  const int wave = threadIdx.x >> 6;
  const int lane = threadIdx.x & 63;
  const int swid = wgl * NWAVES + wave;     // wave id within level slice
  const int r0 = swid, r1 = swid + SLICE_WAVES;   // this wave's 2 rows

  float* hsbuf = ws + WS_HS;
  float* t1b   = ws + WS_T1;
  float* errb  = ws + WS_ERR;
  float* t2b   = ws + WS_T2;
  float* encb  = ws + WS_ENC;
  float*    ctrlf = ws + WS_CTRL;
  unsigned* ctrl  = (unsigned*)(ws + WS_CTRL);

  const float* Wp1 = pw1 + (size_t)lvl * HDIM * HDIM;
  const float* Wp2 = pw2 + (size_t)lvl * HDIM * HDIM;
  const float* We1 = ew1 + (size_t)lvl * HDIM * HDIM;
  const float* We2 = ew2 + (size_t)lvl * HDIM * HDIM;
  const float* Wih = wih + (size_t)lvl * 4 * HDIM * HDIM;
  const float* bp1 = pb1 + lvl * HDIM;
  const float* bp2 = pb2 + lvl * HDIM;
  const float* be1 = eb1 + lvl * HDIM;
  const float* be2 = eb2 + lvl * HDIM;
  const float* qwl = qw + lvl * HDIM;
  const float* bi  = bih + lvl * 4 * HDIM;
  const float* bh  = bhh + lvl * 4 * HDIM;

  unsigned bk = 0;          // barrier index (identical sequence in every WG)
  float fe_local = 0.f;     // per-level fe accumulator (one wave per level uses it)

  for (int r = 0; r < SEQ + NLVL - 1; ++r) {
    const int t = r - lvl;
    const bool act = (t >= 0) && (t < SEQ);

    // ---- P1: t1 = gelu(pw1 @ newh[lvl-1] + pb1)  (lvl >= 1) ----
    if (act && lvl > 0) {
      const float* src = hsbuf + ((t + 1) & 1) * (NLVL * HDIM) + (lvl - 1) * HDIM;
      for (int i = threadIdx.x; i < HDIM; i += THREADS) xl[i] = gload(src + i);
      __syncthreads();
      float d0, d1;
      dot2(Wp1, r0, r1, xl, lane, d0, d1);
      if (lane == 0) {
        gstore(t1b + lvl * HDIM + r0, gelu_f(d0 + bp1[r0]));
        gstore(t1b + lvl * HDIM + r1, gelu_f(d1 + bp1[r1]));
      }
    }
    gbar(ctrl, ++bk, wg);

    // ---- P2: pred = pw2 @ t1 + pb2 ; err = enc[lvl-1] - pred ----
    if (act) {
      if (lvl > 0) {
        const float* src = t1b + lvl * HDIM;
        for (int i = threadIdx.x; i < HDIM; i += THREADS) xl[i] = gload(src + i);
        __syncthreads();
        const float* inp = encb + (lvl - 1) * HDIM;
        float d0, d1;
        dot2(Wp2, r0, r1, xl, lane, d0, d1);
        if (lane == 0) {
          float p0 = d0 + bp2[r0], p1 = d1 + bp2[r1];
          gstore(errb + lvl * HDIM + r0, gload(inp + r0) - p0);
          gstore(errb + lvl * HDIM + r1, gload(inp + r1) - p1);
          if (t == SEQ - 1) { out[lvl * HDIM + r0] = p0; out[lvl * HDIM + r1] = p1; }
        }
      } else if (t == SEQ - 1) {
        // level-0 prediction is identically zero
        for (int i = wgl * THREADS + threadIdx.x; i < HDIM; i += WGS_PER_LVL * THREADS)
          out[i] = 0.f;
      }
    }
    gbar(ctrl, ++bk, wg);

    // ---- P3: t2 = gelu(ew1 @ err + eb1) ; dprec = qw . err + qb ----
    if (act) {
      if (lvl == 0) {
        const float* src = observed + (size_t)t * HDIM;
        for (int i = threadIdx.x; i < HDIM; i += THREADS) xl[i] = src[i];
      } else {
        const float* src = errb + lvl * HDIM;
        for (int i = threadIdx.x; i < HDIM; i += THREADS) xl[i] = gload(src + i);
      }
      __syncthreads();
      float d0, d1;
      dot2(We1, r0, r1, xl, lane, d0, d1);
      if (lane == 0) {
        gstore(t2b + lvl * HDIM + r0, gelu_f(d0 + be1[r0]));
        gstore(t2b + lvl * HDIM + r1, gelu_f(d1 + be1[r1]));
      }
      if (wgl == 0 && wave == 0) {
        float d = dot_row(qwl, xl, lane);
        if (lane == 0) gstore(ctrlf + C_DPREC(lvl), d + qb[lvl]);
      }
    }
    gbar(ctrl, ++bk, wg);

    // ---- P4: enc = ew2 @ t2 + eb2 ----
    if (act) {
      const float* src = t2b + lvl * HDIM;
      for (int i = threadIdx.x; i < HDIM; i += THREADS) xl[i] = gload(src + i);
      __syncthreads();
      float d0, d1;
      dot2(We2, r0, r1, xl, lane, d0, d1);
      if (lane == 0) {
        float e0 = d0 + be2[r0], e1 = d1 + be2[r1];
        gstore(encb + lvl * HDIM + r0, e0);
        gstore(encb + lvl * HDIM + r1, e1);
        if (t == SEQ - 1) {
          out[NLVL * HDIM + lvl * HDIM + r0] = e0;
          out[NLVL * HDIM + lvl * HDIM + r1] = e1;
        }
      }
    }
    gbar(ctrl, ++bk, wg);

    // ---- P5: LSTM cell on upd = hs + prec*enc ; f-gate dead (c0 = 0) ----
    if (act) {
      if (threadIdx.x == 0) s_prec = sigmoid_f(gload(ctrlf + C_DPREC(lvl)));
      __syncthreads();
      const float prec = s_prec;
      const float* hold = hsbuf + (t & 1) * (NLVL * HDIM) + lvl * HDIM;
      const float* el = encb + lvl * HDIM;
      for (int i = threadIdx.x; i < HDIM; i += THREADS)
        xl[i] = fmaf(prec, gload(el + i), gload(hold + i));
      __syncthreads();
      float* hnew = hsbuf + ((t + 1) & 1) * (NLVL * HDIM) + lvl * HDIM;
      // 6 fused row-dots: gates (i,g,o) x rows (r0, r1); f-gate dead.
      {
        const float4* x4  = (const float4*)xl;
        const float4* wiA = (const float4*)(Wih + (size_t)r0 * HDIM);
        const float4* wgA = (const float4*)(Wih + (size_t)(2 * HDIM + r0) * HDIM);
        const float4* woA = (const float4*)(Wih + (size_t)(3 * HDIM + r0) * HDIM);
        const float4* wiB = (const float4*)(Wih + (size_t)r1 * HDIM);
        const float4* wgB = (const float4*)(Wih + (size_t)(2 * HDIM + r1) * HDIM);
        const float4* woB = (const float4*)(Wih + (size_t)(3 * HDIM + r1) * HDIM);
        float aiA = 0.f, agA = 0.f, aoA = 0.f, aiB = 0.f, agB = 0.f, aoB = 0.f;
#pragma unroll
        for (int i = 0; i < HDIM / 4; i += 64) {
          float4 b = x4[i + lane];
          float4 p = wiA[i + lane];
          float4 q = wgA[i + lane];
          float4 u = woA[i + lane];
          float4 p2 = wiB[i + lane];
          float4 q2 = wgB[i + lane];
          float4 u2 = woB[i + lane];
          aiA = fmaf(p.x, b.x, fmaf(p.y, b.y, fmaf(p.z, b.z, fmaf(p.w, b.w, aiA))));
          agA = fmaf(q.x, b.x, fmaf(q.y, b.y, fmaf(q.z, b.z, fmaf(q.w, b.w, agA))));
          aoA = fmaf(u.x, b.x, fmaf(u.y, b.y, fmaf(u.z, b.z, fmaf(u.w, b.w, aoA))));
          aiB = fmaf(p2.x, b.x, fmaf(p2.y, b.y, fmaf(p2.z, b.z, fmaf(p2.w, b.w, aiB))));
          agB = fmaf(q2.x, b.x, fmaf(q2.y, b.y, fmaf(q2.z, b.z, fmaf(q2.w, b.w, agB))));
          aoB = fmaf(u2.x, b.x, fmaf(u2.y, b.y, fmaf(u2.z, b.z, fmaf(u2.w, b.w, aoB))));
        }
        aiA = wredux(aiA); agA = wredux(agA); aoA = wredux(aoA);
        aiB = wredux(aiB); agB = wredux(agB); aoB = wredux(aoB);
        if (lane == 0) {
          float giA = sigmoid_f(aiA + bi[r0] + bh[r0]);
          float ggA = tanhf(agA + bi[2 * HDIM + r0] + bh[2 * HDIM + r0]);
          float goA = sigmoid_f(aoA + bi[3 * HDIM + r0] + bh[3 * HDIM + r0]);
          gstore(hnew + r0, goA * tanhf(giA * ggA));
          float giB = sigmoid_f(aiB + bi[r1] + bh[r1]);
          float ggB = tanhf(agB + bi[2 * HDIM + r1] + bh[2 * HDIM + r1]);
          float goB = sigmoid_f(aoB + bi[3 * HDIM + r1] + bh[3 * HDIM + r1]);
          gstore(hnew + r1, goB * tanhf(giB * ggB));
        }
      }
      if (wgl == 0 && wave == 0) {   // fe += prec * sum(enc^2), register accum
        float s = 0.f;
#pragma unroll
        for (int i = 0; i < HDIM; i += 64) {
          float v = gload(el + i + lane);
          s = fmaf(v, v, s);
        }
        s = wredux(s);
        if (lane == 0) fe_local += prec * s;
      }
    }
    gbar(ctrl, ++bk, wg);
  }

  // publish per-level fe, final barrier, then one thread sums
  if (wgl == 0 && wave == 0 && lane == 0) gstore(ctrlf + C_FEPT(lvl), fe_local);
  gbar(ctrl, ++bk, wg);
  if (wg == 0 && threadIdx.x == 0)
    out[2 * NLVL * HDIM] = gload(ctrlf + C_FEPT(0)) + gload(ctrlf + C_FEPT(1)) +
                           gload(ctrlf + C_FEPT(2)) + gload(ctrlf + C_FEPT(3));
}

extern "C" void kernel_launch(void* const* d_in, const int* in_sizes, int n_in,
                              void* d_out, int out_size, void* d_ws, size_t ws_size,
                              hipStream_t stream) {
  const float* observed = (const float*)d_in[0];
  const float* pw1 = (const float*)d_in[1];
  const float* pb1 = (const float*)d_in[2];
  const float* pw2 = (const float*)d_in[3];
  const float* pb2 = (const float*)d_in[4];
  const float* ew1 = (const float*)d_in[5];
  const float* eb1 = (const float*)d_in[6];
  const float* ew2 = (const float*)d_in[7];
  const float* eb2 = (const float*)d_in[8];
  const float* qw  = (const float*)d_in[9];
  const float* qb  = (const float*)d_in[10];
  const float* wih = (const float*)d_in[11];
  // d_in[12] = whh — unused: h0 == 0 per step, W_hh term vanishes
  const float* bih = (const float*)d_in[13];
  const float* bhh = (const float*)d_in[14];
  float* out = (float*)d_out;
  float* ws  = (float*)d_ws;

  hipLaunchKernelGGL(tpn_init, dim3(32), dim3(256), 0, stream, ws);

  void* args[] = { &observed, &pw1, &pb1, &pw2, &pb2, &ew1, &eb1, &ew2, &eb2,
                   &qw, &qb, &wih, &bih, &bhh, &out, &ws };
  hipLaunchCooperativeKernel((void*)tpn_main, dim3(NWG), dim3(THREADS),
                             args, 0, stream);
}

// Round 4
// 12890.359 us; speedup vs baseline: 5.3186x; 1.5510x over previous
//
#include <hip/hip_runtime.h>
#include <math.h>

// TemporalPredictionNetwork: L=4, S=512, H=1024, B=1.
// Round-3b: per-level barriers (64 arrivals) + bounded-drift (3 rounds)
// producer/consumer gen-flags between adjacent levels; 4-deep round buffers
// for hs/enc. Weight rows prefetched before the x LDS fill.
// (3b fixes: s_sleep requires constant-int operand.)
#define NLVL 4
#define HDIM 1024
#define SEQ  512
#define THREADS 512
#define WGS_PER_LVL 64
#define NWG (NLVL * WGS_PER_LVL)
#define NWAVES (THREADS / 64)
#define SLICE_WAVES (WGS_PER_LVL * NWAVES)   // 512 waves per level
#define NROUND (SEQ + NLVL - 1)

// workspace layout (float offsets)
#define WS_HS4   0                                // [4][NLVL][HDIM] round-buffered h
#define WS_ENC4  (WS_HS4 + 4*NLVL*HDIM)           // [4][NLVL][HDIM] round-buffered enc
#define WS_T1    (WS_ENC4 + 4*NLVL*HDIM)          // [NLVL][HDIM]
#define WS_ERR   (WS_T1 + NLVL*HDIM)
#define WS_T2    (WS_ERR + NLVL*HDIM)
#define WS_CTRL  (WS_T2 + NLVL*HDIM)
#define CTRL_WORDS 320
// ctrl word offsets (64B-strided)
#define C_ARR(l)   ((l)*16)          // per-level arrival counters (monotone)
#define C_GEN(l)   (64 + (l)*16)     // per-level barrier generation = progress clock
#define C_FIN      128
#define C_DPREC(l) (144 + (l)*16)
#define C_FEPT(l)  (208 + (l)*16)

__device__ __forceinline__ float gelu_f(float x) {
  return 0.5f * x * (1.0f + erff(x * 0.70710678118654752f));
}
__device__ __forceinline__ float sigmoid_f(float x) {
  return 1.0f / (1.0f + __expf(-x));
}

// agent-scope relaxed (L2-bypassing, fence-free) accesses
__device__ __forceinline__ float gload(const float* p) {
  return __hip_atomic_load((float*)p, __ATOMIC_RELAXED, __HIP_MEMORY_SCOPE_AGENT);
}
__device__ __forceinline__ void gstore(float* p, float v) {
  __hip_atomic_store(p, v, __ATOMIC_RELAXED, __HIP_MEMORY_SCOPE_AGENT);
}
__device__ __forceinline__ unsigned uload(const unsigned* p) {
  return __hip_atomic_load((unsigned*)p, __ATOMIC_RELAXED, __HIP_MEMORY_SCOPE_AGENT);
}

__device__ __forceinline__ float wredux(float v) {
#pragma unroll
  for (int off = 32; off > 0; off >>= 1) v += __shfl_down(v, off, 64);
  return v;  // valid in lane 0
}

__device__ __forceinline__ float dot4f(float4 a, float4 x, float acc) {
  return fmaf(a.x, x.x, fmaf(a.y, x.y, fmaf(a.z, x.z, fmaf(a.w, x.w, acc))));
}

// wait until *p >= k (thread0 polls, then WG-wide sync)
__device__ __forceinline__ void wait_ge(const unsigned* p, unsigned k) {
  if (threadIdx.x == 0) {
    unsigned cur = uload(p);
    while (cur < k) {
      if (k - cur >= 2u) __builtin_amdgcn_s_sleep(8);
      else               __builtin_amdgcn_s_sleep(1);
      cur = uload(p);
    }
  }
  __syncthreads();
}

// per-level barrier over 64 WGs; monotone counter; gen = barrier count
__device__ __forceinline__ void lbar(unsigned* arr, unsigned* gen, unsigned k) {
  asm volatile("s_waitcnt vmcnt(0)" ::: "memory");
  __syncthreads();
  if (threadIdx.x == 0) {
    unsigned old = __hip_atomic_fetch_add(arr, 1u, __ATOMIC_RELAXED,
                                          __HIP_MEMORY_SCOPE_AGENT);
    if (old == (unsigned)WGS_PER_LVL * k - 1u) {
      __hip_atomic_store(gen, k, __ATOMIC_RELAXED, __HIP_MEMORY_SCOPE_AGENT);
    } else {
      unsigned cur = uload(gen);
      while (cur < k) {
        __builtin_amdgcn_s_sleep(1);
        cur = uload(gen);
      }
    }
  }
  __syncthreads();
}

// matvec: rows r0,r1 of W against shared vector src (via LDS xl).
// Weight fragments prefetched BEFORE the x fill to overlap latencies.
__device__ __forceinline__ void phase_mv2(
    const float* __restrict__ W, int r0, int r1,
    const float* __restrict__ src, bool uc,
    float* __restrict__ xl, int lane, float& o0, float& o1)
{
  const float4* __restrict__ w0 = (const float4*)W + (size_t)r0 * (HDIM / 4);
  const float4* __restrict__ w1 = (const float4*)W + (size_t)r1 * (HDIM / 4);
  float4 A0 = w0[lane], A1 = w0[lane + 64], A2 = w0[lane + 128], A3 = w0[lane + 192];
  float4 B0 = w1[lane], B1 = w1[lane + 64], B2 = w1[lane + 128], B3 = w1[lane + 192];
  int i0 = threadIdx.x, i1 = threadIdx.x + THREADS;
  float v0 = uc ? gload(src + i0) : src[i0];
  float v1 = uc ? gload(src + i1) : src[i1];
  xl[i0] = v0; xl[i1] = v1;
  __syncthreads();
  const float4* x4 = (const float4*)xl;
  float4 X0 = x4[lane], X1 = x4[lane + 64], X2 = x4[lane + 128], X3 = x4[lane + 192];
  float a = dot4f(A0, X0, 0.f); a = dot4f(A1, X1, a);
  a = dot4f(A2, X2, a);         a = dot4f(A3, X3, a);
  float b = dot4f(B0, X0, 0.f); b = dot4f(B1, X1, b);
  b = dot4f(B2, X2, b);         b = dot4f(B3, X3, b);
  o0 = wredux(a); o1 = wredux(b);
}

extern "C" __global__ void tpn_init(float* ws) {
  int i = blockIdx.x * blockDim.x + threadIdx.x;
  int n = blockDim.x * gridDim.x;
  for (int k = i; k < 4 * NLVL * HDIM; k += n) ws[WS_HS4 + k] = 0.f;
  for (int k = i; k < CTRL_WORDS; k += n) ws[WS_CTRL + k] = 0.f;
}

extern "C" __global__ void __launch_bounds__(THREADS) tpn_main(
    const float* __restrict__ observed,
    const float* __restrict__ pw1, const float* __restrict__ pb1,
    const float* __restrict__ pw2, const float* __restrict__ pb2,
    const float* __restrict__ ew1, const float* __restrict__ eb1,
    const float* __restrict__ ew2, const float* __restrict__ eb2,
    const float* __restrict__ qw,  const float* __restrict__ qb,
    const float* __restrict__ wih, const float* __restrict__ bih,
    const float* __restrict__ bhh,
    float* __restrict__ out, float* __restrict__ ws)
{
  __shared__ __align__(16) float xl[HDIM];
  __shared__ float s_prec;
  __shared__ float sred[NWAVES];
  const int wg   = blockIdx.x;
  const int lvl  = wg / WGS_PER_LVL;
  const int wgl  = wg % WGS_PER_LVL;
  const int wave = threadIdx.x >> 6;
  const int lane = threadIdx.x & 63;
  const int swid = wgl * NWAVES + wave;
  const int r0 = swid, r1 = swid + SLICE_WAVES;

  float* hs4  = ws + WS_HS4;
  float* enc4 = ws + WS_ENC4;
  float* t1b  = ws + WS_T1;
  float* errb = ws + WS_ERR;
  float* t2b  = ws + WS_T2;
  float*    ctrlf = ws + WS_CTRL;
  unsigned* ctrl  = (unsigned*)(ws + WS_CTRL);
  unsigned* myarr = ctrl + C_ARR(lvl);
  unsigned* mygen = ctrl + C_GEN(lvl);
  unsigned* upgen = (lvl > 0)        ? ctrl + C_GEN(lvl - 1) : nullptr;
  unsigned* dngen = (lvl < NLVL - 1) ? ctrl + C_GEN(lvl + 1) : nullptr;

  const float* Wp1 = pw1 + (size_t)lvl * HDIM * HDIM;
  const float* Wp2 = pw2 + (size_t)lvl * HDIM * HDIM;
  const float* We1 = ew1 + (size_t)lvl * HDIM * HDIM;
  const float* We2 = ew2 + (size_t)lvl * HDIM * HDIM;
  const float* Wih = wih + (size_t)lvl * 4 * HDIM * HDIM;
  const float* bp1 = pb1 + lvl * HDIM;
  const float* bp2 = pb2 + lvl * HDIM;
  const float* be1 = eb1 + lvl * HDIM;
  const float* be2 = eb2 + lvl * HDIM;
  const float* qwl = qw + lvl * HDIM;
  const float* bi  = bih + lvl * 4 * HDIM;
  const float* bh  = bhh + lvl * 4 * HDIM;

  unsigned bk = 0;
  float fe_local = 0.f;

  for (int r = 0; r < NROUND; ++r) {
    const int t = r - lvl;
    const bool act = (t >= 0) && (t < SEQ);

    // ---- P1: t1 = gelu(pw1 @ h[lvl-1, r-1] + pb1) ----
    if (act && lvl > 0) {
      wait_ge(upgen, (unsigned)(5 * r));   // upstream finished round r-1 fully
      const float* src = hs4 + (((r - 1) & 3) * NLVL + (lvl - 1)) * HDIM;
      float o0, o1;
      phase_mv2(Wp1, r0, r1, src, true, xl, lane, o0, o1);
      if (lane == 0) {
        gstore(t1b + lvl * HDIM + r0, gelu_f(o0 + bp1[r0]));
        gstore(t1b + lvl * HDIM + r1, gelu_f(o1 + bp1[r1]));
      }
    }
    lbar(myarr, mygen, ++bk);

    // ---- P2: pred = pw2 @ t1 + pb2 ; err = enc[lvl-1, r-1] - pred ----
    if (act) {
      if (lvl > 0) {
        const float* inp = enc4 + (((r - 1) & 3) * NLVL + (lvl - 1)) * HDIM;
        float ep0 = 0.f, ep1 = 0.f;
        if (lane == 0) { ep0 = gload(inp + r0); ep1 = gload(inp + r1); }
        float o0, o1;
        phase_mv2(Wp2, r0, r1, t1b + lvl * HDIM, true, xl, lane, o0, o1);
        if (lane == 0) {
          float p0 = o0 + bp2[r0], p1 = o1 + bp2[r1];
          gstore(errb + lvl * HDIM + r0, ep0 - p0);
          gstore(errb + lvl * HDIM + r1, ep1 - p1);
          if (t == SEQ - 1) { out[lvl * HDIM + r0] = p0; out[lvl * HDIM + r1] = p1; }
        }
      } else if (t == SEQ - 1) {
        for (int i = wgl * THREADS + threadIdx.x; i < HDIM; i += WGS_PER_LVL * THREADS)
          out[i] = 0.f;
      }
    }
    lbar(myarr, mygen, ++bk);

    // ---- P3: t2 = gelu(ew1 @ err + eb1) ; dprec = qw . err + qb ----
    if (act) {
      float4 Q0, Q1, Q2, Q3;
      const bool doq = (wgl == 0 && wave == 0);
      if (doq) {
        const float4* q4 = (const float4*)qwl;
        Q0 = q4[lane]; Q1 = q4[lane + 64]; Q2 = q4[lane + 128]; Q3 = q4[lane + 192];
      }
      const float* src = (lvl == 0) ? (observed + (size_t)t * HDIM)
                                    : (errb + lvl * HDIM);
      float o0, o1;
      phase_mv2(We1, r0, r1, src, lvl > 0, xl, lane, o0, o1);
      if (lane == 0) {
        gstore(t2b + lvl * HDIM + r0, gelu_f(o0 + be1[r0]));
        gstore(t2b + lvl * HDIM + r1, gelu_f(o1 + be1[r1]));
      }
      if (doq) {
        const float4* x4 = (const float4*)xl;
        float d = dot4f(Q0, x4[lane], 0.f);
        d = dot4f(Q1, x4[lane + 64], d);
        d = dot4f(Q2, x4[lane + 128], d);
        d = dot4f(Q3, x4[lane + 192], d);
        d = wredux(d);
        if (lane == 0) gstore(ctrlf + C_DPREC(lvl), d + qb[lvl]);
      }
    }
    lbar(myarr, mygen, ++bk);

    // ---- P4: enc = ew2 @ t2 + eb2  (writes round-buffer r&3) ----
    if (act) {
      if (lvl < NLVL - 1 && r >= 3)
        wait_ge(dngen, (unsigned)(5 * r - 13));  // downstream consumed buf r&3
      float o0, o1;
      phase_mv2(We2, r0, r1, t2b + lvl * HDIM, true, xl, lane, o0, o1);
      float* dst = enc4 + (((r) & 3) * NLVL + lvl) * HDIM;
      if (lane == 0) {
        float e0 = o0 + be2[r0], e1 = o1 + be2[r1];
        gstore(dst + r0, e0);
        gstore(dst + r1, e1);
        if (t == SEQ - 1) {
          out[NLVL * HDIM + lvl * HDIM + r0] = e0;
          out[NLVL * HDIM + lvl * HDIM + r1] = e1;
        }
      }
    }
    lbar(myarr, mygen, ++bk);

    // ---- P5: LSTM on upd = hs + prec*enc ; f-gate dead (c0 = 0) ----
    if (act) {
      // prefetch 6 gate rows (i,g,o) x (r0,r1)
      const float* Wr[6] = {
        Wih + (size_t)r0 * HDIM, Wih + (size_t)(2 * HDIM + r0) * HDIM,
        Wih + (size_t)(3 * HDIM + r0) * HDIM,
        Wih + (size_t)r1 * HDIM, Wih + (size_t)(2 * HDIM + r1) * HDIM,
        Wih + (size_t)(3 * HDIM + r1) * HDIM };
      float4 Wf[6][4];
#pragma unroll
      for (int k = 0; k < 6; ++k) {
        const float4* w = (const float4*)Wr[k];
        Wf[k][0] = w[lane]; Wf[k][1] = w[lane + 64];
        Wf[k][2] = w[lane + 128]; Wf[k][3] = w[lane + 192];
      }
      const float* el   = enc4 + (((r) & 3) * NLVL + lvl) * HDIM;
      const float* hold = hs4 + (((r - 1) & 3) * NLVL + lvl) * HDIM;
      int i0 = threadIdx.x, i1 = threadIdx.x + THREADS;
      float e0 = gload(el + i0), h0 = gload(hold + i0);
      float e1 = gload(el + i1), h1 = gload(hold + i1);
      if (threadIdx.x == 0) s_prec = sigmoid_f(gload(ctrlf + C_DPREC(lvl)));
      __syncthreads();
      const float pr = s_prec;
      xl[i0] = fmaf(pr, e0, h0);
      xl[i1] = fmaf(pr, e1, h1);
      __syncthreads();
      const float4* x4 = (const float4*)xl;
      float4 X[4] = { x4[lane], x4[lane + 64], x4[lane + 128], x4[lane + 192] };
      float d[6];
#pragma unroll
      for (int k = 0; k < 6; ++k) {
        float a = dot4f(Wf[k][0], X[0], 0.f);
        a = dot4f(Wf[k][1], X[1], a);
        a = dot4f(Wf[k][2], X[2], a);
        a = dot4f(Wf[k][3], X[3], a);
        d[k] = wredux(a);
      }
      float* hnew = hs4 + (((r) & 3) * NLVL + lvl) * HDIM;
      if (lane == 0) {
        float gi0 = sigmoid_f(d[0] + bi[r0] + bh[r0]);
        float gg0 = tanhf(d[1] + bi[2 * HDIM + r0] + bh[2 * HDIM + r0]);
        float go0 = sigmoid_f(d[2] + bi[3 * HDIM + r0] + bh[3 * HDIM + r0]);
        gstore(hnew + r0, go0 * tanhf(gi0 * gg0));
        float gi1 = sigmoid_f(d[3] + bi[r1] + bh[r1]);
        float gg1 = tanhf(d[4] + bi[2 * HDIM + r1] + bh[2 * HDIM + r1]);
        float go1 = sigmoid_f(d[5] + bi[3 * HDIM + r1] + bh[3 * HDIM + r1]);
        gstore(hnew + r1, go1 * tanhf(gi1 * gg1));
      }
      // fe += prec * sum(enc^2): WG0 threads already hold the full enc vector
      if (wgl == 0) {
        float s = fmaf(e0, e0, e1 * e1);
        s = wredux(s);
        if (lane == 0) sred[wave] = s;
        __syncthreads();
        if (threadIdx.x == 0) {
          float tot = 0.f;
#pragma unroll
          for (int k = 0; k < NWAVES; ++k) tot += sred[k];
          fe_local += pr * tot;
        }
      }
    }
    lbar(myarr, mygen, ++bk);
  }

  // publish per-level fe; one leader sums after all four arrive
  if (wgl == 0 && threadIdx.x == 0) {
    gstore(ctrlf + C_FEPT(lvl), fe_local);
    asm volatile("s_waitcnt vmcnt(0)" ::: "memory");
    __hip_atomic_fetch_add(ctrl + C_FIN, 1u, __ATOMIC_RELAXED,
                           __HIP_MEMORY_SCOPE_AGENT);
  }
  if (wg == 0 && threadIdx.x == 0) {
    while (uload(ctrl + C_FIN) < (unsigned)NLVL) __builtin_amdgcn_s_sleep(1);
    out[2 * NLVL * HDIM] = gload(ctrlf + C_FEPT(0)) + gload(ctrlf + C_FEPT(1)) +
                           gload(ctrlf + C_FEPT(2)) + gload(ctrlf + C_FEPT(3));
  }
}

extern "C" void kernel_launch(void* const* d_in, const int* in_sizes, int n_in,
                              void* d_out, int out_size, void* d_ws, size_t ws_size,
                              hipStream_t stream) {
  const float* observed = (const float*)d_in[0];
  const float* pw1 = (const float*)d_in[1];
  const float* pb1 = (const float*)d_in[2];
  const float* pw2 = (const float*)d_in[3];
  const float* pb2 = (const float*)d_in[4];
  const float* ew1 = (const float*)d_in[5];
  const float* eb1 = (const float*)d_in[6];
  const float* ew2 = (const float*)d_in[7];
  const float* eb2 = (const float*)d_in[8];
  const float* qw  = (const float*)d_in[9];
  const float* qb  = (const float*)d_in[10];
  const float* wih = (const float*)d_in[11];
  // d_in[12] = whh — unused (h0 == 0 per step)
  const float* bih = (const float*)d_in[13];
  const float* bhh = (const float*)d_in[14];
  float* out = (float*)d_out;
  float* ws  = (float*)d_ws;

  hipLaunchKernelGGL(tpn_init, dim3(64), dim3(256), 0, stream, ws);

  void* args[] = { &observed, &pw1, &pb1, &pw2, &pb2, &ew1, &eb1, &ew2, &eb2,
                   &qw, &qb, &wih, &bih, &bhh, &out, &ws };
  (void)hipLaunchCooperativeKernel((void*)tpn_main, dim3(NWG), dim3(THREADS),
                                   args, 0, stream);
}

// Round 5
// 11307.587 us; speedup vs baseline: 6.0631x; 1.1400x over previous
//
#include <hip/hip_runtime.h>
#include <math.h>

// TemporalPredictionNetwork: L=4, S=512, H=1024, B=1.
// Round-5: bf16 weight cache in d_ws (halves the per-round weight stream,
// which round-4 counters showed is the floor: 5 phases x 64KB/CU fp32).
// Activations/biases/accumulation stay fp32. Falls back to fp32 weights if
// ws_size is too small. Sync structure identical to round-4 (per-level
// barriers + bounded drift, fence-free agent-scope atomics).
#define NLVL 4
#define HDIM 1024
#define SEQ  512
#define THREADS 512
#define WGS_PER_LVL 64
#define NWG (NLVL * WGS_PER_LVL)
#define NWAVES (THREADS / 64)
#define SLICE_WAVES (WGS_PER_LVL * NWAVES)   // 512 waves per level
#define NROUND (SEQ + NLVL - 1)

typedef unsigned short u16;
typedef unsigned int   u32;

// workspace layout (float offsets)
#define WS_HS4   0                                // [4][NLVL][HDIM]
#define WS_ENC4  (WS_HS4 + 4*NLVL*HDIM)           // [4][NLVL][HDIM]
#define WS_T1    (WS_ENC4 + 4*NLVL*HDIM)          // [NLVL][HDIM]
#define WS_ERR   (WS_T1 + NLVL*HDIM)
#define WS_T2    (WS_ERR + NLVL*HDIM)
#define WS_CTRL  (WS_T2 + NLVL*HDIM)
#define CTRL_WORDS 320
#define WS_BF16  (WS_CTRL + CTRL_WORDS)           // bf16 weight cache (u16 units below)
// ctrl word offsets (64B-strided)
#define C_ARR(l)   ((l)*16)
#define C_GEN(l)   (64 + (l)*16)
#define C_FIN      128
#define C_DPREC(l) (144 + (l)*16)
#define C_FEPT(l)  (208 + (l)*16)
// bf16 region offsets (u16 units)
#define BW_SQ   (NLVL * HDIM * HDIM)              // 4,194,304 per square matrix
#define BW_P1   0
#define BW_P2   (BW_P1 + BW_SQ)
#define BW_E1   (BW_P2 + BW_SQ)
#define BW_E2   (BW_E1 + BW_SQ)
#define BW_IH   (BW_E2 + BW_SQ)                   // L x 3H x H (gates i,g,o)
#define BW_IH_N (NLVL * 3 * HDIM * HDIM)
#define BW_TOTAL (BW_IH + BW_IH_N)                // 29,360,128 u16 = 56 MiB

__device__ __forceinline__ float gelu_f(float x) {
  return 0.5f * x * (1.0f + erff(x * 0.70710678118654752f));
}
__device__ __forceinline__ float sigmoid_f(float x) {
  return 1.0f / (1.0f + __expf(-x));
}

// agent-scope relaxed (fence-free) accesses
__device__ __forceinline__ float gload(const float* p) {
  return __hip_atomic_load((float*)p, __ATOMIC_RELAXED, __HIP_MEMORY_SCOPE_AGENT);
}
__device__ __forceinline__ void gstore(float* p, float v) {
  __hip_atomic_store(p, v, __ATOMIC_RELAXED, __HIP_MEMORY_SCOPE_AGENT);
}
__device__ __forceinline__ unsigned uload(const unsigned* p) {
  return __hip_atomic_load((unsigned*)p, __ATOMIC_RELAXED, __HIP_MEMORY_SCOPE_AGENT);
}

__device__ __forceinline__ float wredux(float v) {
#pragma unroll
  for (int off = 32; off > 0; off >>= 1) v += __shfl_down(v, off, 64);
  return v;
}

__device__ __forceinline__ float dot4f(float4 a, float4 x, float acc) {
  return fmaf(a.x, x.x, fmaf(a.y, x.y, fmaf(a.z, x.z, fmaf(a.w, x.w, acc))));
}
// bf16-pair helpers: element j in bits[15:0], j+1 in bits[31:16]
__device__ __forceinline__ float bflo(u32 u) { return __uint_as_float(u << 16); }
__device__ __forceinline__ float bfhi(u32 u) { return __uint_as_float(u & 0xffff0000u); }
__device__ __forceinline__ float bdot(uint2 u, float4 x, float acc) {
  acc = fmaf(bflo(u.x), x.x, acc); acc = fmaf(bfhi(u.x), x.y, acc);
  acc = fmaf(bflo(u.y), x.z, acc); acc = fmaf(bfhi(u.y), x.w, acc);
  return acc;
}
__device__ __forceinline__ u16 f2bf(float f) {   // RNE; weights are small normals
  u32 b = __float_as_uint(f);
  return (u16)((b + 0x7fffu + ((b >> 16) & 1u)) >> 16);
}

__device__ __forceinline__ void wait_ge(const unsigned* p, unsigned k) {
  if (threadIdx.x == 0) {
    unsigned cur = uload(p);
    while (cur < k) {
      if (k - cur >= 2u) __builtin_amdgcn_s_sleep(8);
      else               __builtin_amdgcn_s_sleep(1);
      cur = uload(p);
    }
  }
  __syncthreads();
}

__device__ __forceinline__ void lbar(unsigned* arr, unsigned* gen, unsigned k) {
  asm volatile("s_waitcnt vmcnt(0)" ::: "memory");
  __syncthreads();
  if (threadIdx.x == 0) {
    unsigned old = __hip_atomic_fetch_add(arr, 1u, __ATOMIC_RELAXED,
                                          __HIP_MEMORY_SCOPE_AGENT);
    if (old == (unsigned)WGS_PER_LVL * k - 1u) {
      __hip_atomic_store(gen, k, __ATOMIC_RELAXED, __HIP_MEMORY_SCOPE_AGENT);
    } else {
      unsigned cur = uload(gen);
      while (cur < k) {
        __builtin_amdgcn_s_sleep(1);
        cur = uload(gen);
      }
    }
  }
  __syncthreads();
}

// matvec of rows r0,r1 against shared vector src (via LDS xl); weights
// prefetched before the x fill. BF16 selects u16 weight rows.
template <bool BF16>
__device__ __forceinline__ void phase_mv2(
    const float* __restrict__ Wf, const u16* __restrict__ Wb, int r0, int r1,
    const float* __restrict__ src, bool uc,
    float* __restrict__ xl, int lane, float& o0, float& o1)
{
  float4 A0, A1, A2, A3, B0, B1, B2, B3;
  uint2  a0, a1, a2, a3, b0, b1, b2, b3;
  if constexpr (BF16) {
    const uint2* w0 = (const uint2*)(Wb + (size_t)r0 * HDIM);
    const uint2* w1 = (const uint2*)(Wb + (size_t)r1 * HDIM);
    a0 = w0[lane]; a1 = w0[lane + 64]; a2 = w0[lane + 128]; a3 = w0[lane + 192];
    b0 = w1[lane]; b1 = w1[lane + 64]; b2 = w1[lane + 128]; b3 = w1[lane + 192];
  } else {
    const float4* w0 = (const float4*)(Wf + (size_t)r0 * HDIM);
    const float4* w1 = (const float4*)(Wf + (size_t)r1 * HDIM);
    A0 = w0[lane]; A1 = w0[lane + 64]; A2 = w0[lane + 128]; A3 = w0[lane + 192];
    B0 = w1[lane]; B1 = w1[lane + 64]; B2 = w1[lane + 128]; B3 = w1[lane + 192];
  }
  int i0 = threadIdx.x, i1 = threadIdx.x + THREADS;
  float v0 = uc ? gload(src + i0) : src[i0];
  float v1 = uc ? gload(src + i1) : src[i1];
  xl[i0] = v0; xl[i1] = v1;
  __syncthreads();
  const float4* x4 = (const float4*)xl;
  float4 X0 = x4[lane], X1 = x4[lane + 64], X2 = x4[lane + 128], X3 = x4[lane + 192];
  float a, b;
  if constexpr (BF16) {
    a = bdot(a0, X0, 0.f); a = bdot(a1, X1, a); a = bdot(a2, X2, a); a = bdot(a3, X3, a);
    b = bdot(b0, X0, 0.f); b = bdot(b1, X1, b); b = bdot(b2, X2, b); b = bdot(b3, X3, b);
  } else {
    a = dot4f(A0, X0, 0.f); a = dot4f(A1, X1, a); a = dot4f(A2, X2, a); a = dot4f(A3, X3, a);
    b = dot4f(B0, X0, 0.f); b = dot4f(B1, X1, b); b = dot4f(B2, X2, b); b = dot4f(B3, X3, b);
  }
  o0 = wredux(a); o1 = wredux(b);
}

extern "C" __global__ void tpn_init(float* ws) {
  int i = blockIdx.x * blockDim.x + threadIdx.x;
  int n = blockDim.x * gridDim.x;
  for (int k = i; k < 4 * NLVL * HDIM; k += n) ws[WS_HS4 + k] = 0.f;
  for (int k = i; k < CTRL_WORDS; k += n) ws[WS_CTRL + k] = 0.f;
}

// fp32 -> bf16 (RNE), contiguous
extern "C" __global__ void cvt_sq(const float* __restrict__ src,
                                  u16* __restrict__ dst, int n) {
  int i = blockIdx.x * blockDim.x + threadIdx.x;
  int stride = blockDim.x * gridDim.x;
  for (; i < n; i += stride) dst[i] = f2bf(src[i]);
}

// wih [L][4H][H] -> compact [L][3H][H] keeping gates {i=0, g=2, o=3}
extern "C" __global__ void cvt_ih(const float* __restrict__ wih,
                                  u16* __restrict__ dst) {
  int i = blockIdx.x * blockDim.x + threadIdx.x;
  int stride = blockDim.x * gridDim.x;
  const int per_lvl = 3 * HDIM * HDIM;
  for (; i < NLVL * per_lvl; i += stride) {
    int l = i / per_lvl;
    int rem = i - l * per_lvl;
    int gd = rem / (HDIM * HDIM);
    int rr = rem - gd * (HDIM * HDIM);
    int gs = (gd == 0) ? 0 : gd + 1;            // 0->i, 1->g, 2->o
    dst[i] = f2bf(wih[((size_t)(l * 4 + gs) * HDIM) * HDIM + rr]);
  }
}

template <bool BF16>
__global__ void __launch_bounds__(THREADS) tpn_main_t(
    const float* __restrict__ observed,
    const float* __restrict__ pw1, const float* __restrict__ pb1,
    const float* __restrict__ pw2, const float* __restrict__ pb2,
    const float* __restrict__ ew1, const float* __restrict__ eb1,
    const float* __restrict__ ew2, const float* __restrict__ eb2,
    const float* __restrict__ qw,  const float* __restrict__ qb,
    const float* __restrict__ wih, const float* __restrict__ bih,
    const float* __restrict__ bhh,
    float* __restrict__ out, float* __restrict__ ws,
    const u16* __restrict__ bw)
{
  __shared__ __align__(16) float xl[HDIM];
  __shared__ float s_prec;
  __shared__ float sred[NWAVES];
  const int wg   = blockIdx.x;
  const int lvl  = wg / WGS_PER_LVL;
  const int wgl  = wg % WGS_PER_LVL;
  const int wave = threadIdx.x >> 6;
  const int lane = threadIdx.x & 63;
  const int swid = wgl * NWAVES + wave;
  const int r0 = swid, r1 = swid + SLICE_WAVES;

  float* hs4  = ws + WS_HS4;
  float* enc4 = ws + WS_ENC4;
  float* t1b  = ws + WS_T1;
  float* errb = ws + WS_ERR;
  float* t2b  = ws + WS_T2;
  float*    ctrlf = ws + WS_CTRL;
  unsigned* ctrl  = (unsigned*)(ws + WS_CTRL);
  unsigned* myarr = ctrl + C_ARR(lvl);
  unsigned* mygen = ctrl + C_GEN(lvl);
  unsigned* upgen = (lvl > 0)        ? ctrl + C_GEN(lvl - 1) : nullptr;
  unsigned* dngen = (lvl < NLVL - 1) ? ctrl + C_GEN(lvl + 1) : nullptr;

  // fp32 weight bases (fallback) and bf16 bases (primary)
  const float* Wp1 = pw1 + (size_t)lvl * HDIM * HDIM;
  const float* Wp2 = pw2 + (size_t)lvl * HDIM * HDIM;
  const float* We1 = ew1 + (size_t)lvl * HDIM * HDIM;
  const float* We2 = ew2 + (size_t)lvl * HDIM * HDIM;
  const float* Wih = wih + (size_t)lvl * 4 * HDIM * HDIM;
  const u16* Bp1 = bw + BW_P1 + (size_t)lvl * HDIM * HDIM;
  const u16* Bp2 = bw + BW_P2 + (size_t)lvl * HDIM * HDIM;
  const u16* Be1 = bw + BW_E1 + (size_t)lvl * HDIM * HDIM;
  const u16* Be2 = bw + BW_E2 + (size_t)lvl * HDIM * HDIM;
  const u16* Bih = bw + BW_IH + (size_t)lvl * 3 * HDIM * HDIM;
  const float* bp1 = pb1 + lvl * HDIM;
  const float* bp2 = pb2 + lvl * HDIM;
  const float* be1 = eb1 + lvl * HDIM;
  const float* be2 = eb2 + lvl * HDIM;
  const float* qwl = qw + lvl * HDIM;
  const float* bi  = bih + lvl * 4 * HDIM;
  const float* bh  = bhh + lvl * 4 * HDIM;

  unsigned bk = 0;
  float fe_local = 0.f;

  for (int r = 0; r < NROUND; ++r) {
    const int t = r - lvl;
    const bool act = (t >= 0) && (t < SEQ);

    // ---- P1: t1 = gelu(pw1 @ h[lvl-1, r-1] + pb1) ----
    if (act && lvl > 0) {
      wait_ge(upgen, (unsigned)(5 * r));
      const float* src = hs4 + (((r - 1) & 3) * NLVL + (lvl - 1)) * HDIM;
      float o0, o1;
      phase_mv2<BF16>(Wp1, Bp1, r0, r1, src, true, xl, lane, o0, o1);
      if (lane == 0) {
        gstore(t1b + lvl * HDIM + r0, gelu_f(o0 + bp1[r0]));
        gstore(t1b + lvl * HDIM + r1, gelu_f(o1 + bp1[r1]));
      }
    }
    lbar(myarr, mygen, ++bk);

    // ---- P2: pred = pw2 @ t1 + pb2 ; err = enc[lvl-1, r-1] - pred ----
    if (act) {
      if (lvl > 0) {
        const float* inp = enc4 + (((r - 1) & 3) * NLVL + (lvl - 1)) * HDIM;
        float ep0 = 0.f, ep1 = 0.f;
        if (lane == 0) { ep0 = gload(inp + r0); ep1 = gload(inp + r1); }
        float o0, o1;
        phase_mv2<BF16>(Wp2, Bp2, r0, r1, t1b + lvl * HDIM, true, xl, lane, o0, o1);
        if (lane == 0) {
          float p0 = o0 + bp2[r0], p1 = o1 + bp2[r1];
          gstore(errb + lvl * HDIM + r0, ep0 - p0);
          gstore(errb + lvl * HDIM + r1, ep1 - p1);
          if (t == SEQ - 1) { out[lvl * HDIM + r0] = p0; out[lvl * HDIM + r1] = p1; }
        }
      } else if (t == SEQ - 1) {
        for (int i = wgl * THREADS + threadIdx.x; i < HDIM; i += WGS_PER_LVL * THREADS)
          out[i] = 0.f;
      }
    }
    lbar(myarr, mygen, ++bk);

    // ---- P3: t2 = gelu(ew1 @ err + eb1) ; dprec = qw . err + qb ----
    if (act) {
      float4 Q0, Q1, Q2, Q3;
      const bool doq = (wgl == 0 && wave == 0);
      if (doq) {
        const float4* q4 = (const float4*)qwl;
        Q0 = q4[lane]; Q1 = q4[lane + 64]; Q2 = q4[lane + 128]; Q3 = q4[lane + 192];
      }
      const float* src = (lvl == 0) ? (observed + (size_t)t * HDIM)
                                    : (errb + lvl * HDIM);
      float o0, o1;
      phase_mv2<BF16>(We1, Be1, r0, r1, src, lvl > 0, xl, lane, o0, o1);
      if (lane == 0) {
        gstore(t2b + lvl * HDIM + r0, gelu_f(o0 + be1[r0]));
        gstore(t2b + lvl * HDIM + r1, gelu_f(o1 + be1[r1]));
      }
      if (doq) {
        const float4* x4 = (const float4*)xl;
        float d = dot4f(Q0, x4[lane], 0.f);
        d = dot4f(Q1, x4[lane + 64], d);
        d = dot4f(Q2, x4[lane + 128], d);
        d = dot4f(Q3, x4[lane + 192], d);
        d = wredux(d);
        if (lane == 0) gstore(ctrlf + C_DPREC(lvl), d + qb[lvl]);
      }
    }
    lbar(myarr, mygen, ++bk);

    // ---- P4: enc = ew2 @ t2 + eb2  (writes round-buffer r&3) ----
    if (act) {
      if (lvl < NLVL - 1 && r >= 3)
        wait_ge(dngen, (unsigned)(5 * r - 13));
      float o0, o1;
      phase_mv2<BF16>(We2, Be2, r0, r1, t2b + lvl * HDIM, true, xl, lane, o0, o1);
      float* dst = enc4 + (((r) & 3) * NLVL + lvl) * HDIM;
      if (lane == 0) {
        float e0 = o0 + be2[r0], e1 = o1 + be2[r1];
        gstore(dst + r0, e0);
        gstore(dst + r1, e1);
        if (t == SEQ - 1) {
          out[NLVL * HDIM + lvl * HDIM + r0] = e0;
          out[NLVL * HDIM + lvl * HDIM + r1] = e1;
        }
      }
    }
    lbar(myarr, mygen, ++bk);

    // ---- P5: LSTM on upd = hs + prec*enc ; f-gate dead (c0 = 0) ----
    if (act) {
      // prefetch 6 gate rows (i,g,o) x (r0,r1)
      float4 Wf[6][4];
      uint2  Wb[6][4];
      if constexpr (BF16) {
        const u16* Rr[6] = {
          Bih + (size_t)r0 * HDIM, Bih + (size_t)(HDIM + r0) * HDIM,
          Bih + (size_t)(2 * HDIM + r0) * HDIM,
          Bih + (size_t)r1 * HDIM, Bih + (size_t)(HDIM + r1) * HDIM,
          Bih + (size_t)(2 * HDIM + r1) * HDIM };
#pragma unroll
        for (int k = 0; k < 6; ++k) {
          const uint2* w = (const uint2*)Rr[k];
          Wb[k][0] = w[lane]; Wb[k][1] = w[lane + 64];
          Wb[k][2] = w[lane + 128]; Wb[k][3] = w[lane + 192];
        }
      } else {
        const float* Rr[6] = {
          Wih + (size_t)r0 * HDIM, Wih + (size_t)(2 * HDIM + r0) * HDIM,
          Wih + (size_t)(3 * HDIM + r0) * HDIM,
          Wih + (size_t)r1 * HDIM, Wih + (size_t)(2 * HDIM + r1) * HDIM,
          Wih + (size_t)(3 * HDIM + r1) * HDIM };
#pragma unroll
        for (int k = 0; k < 6; ++k) {
          const float4* w = (const float4*)Rr[k];
          Wf[k][0] = w[lane]; Wf[k][1] = w[lane + 64];
          Wf[k][2] = w[lane + 128]; Wf[k][3] = w[lane + 192];
        }
      }
      const float* el   = enc4 + (((r) & 3) * NLVL + lvl) * HDIM;
      const float* hold = hs4 + (((r - 1) & 3) * NLVL + lvl) * HDIM;
      int i0 = threadIdx.x, i1 = threadIdx.x + THREADS;
      float e0 = gload(el + i0), h0 = gload(hold + i0);
      float e1 = gload(el + i1), h1 = gload(hold + i1);
      if (threadIdx.x == 0) s_prec = sigmoid_f(gload(ctrlf + C_DPREC(lvl)));
      __syncthreads();
      const float pr = s_prec;
      xl[i0] = fmaf(pr, e0, h0);
      xl[i1] = fmaf(pr, e1, h1);
      __syncthreads();
      const float4* x4 = (const float4*)xl;
      float4 X[4] = { x4[lane], x4[lane + 64], x4[lane + 128], x4[lane + 192] };
      float d[6];
#pragma unroll
      for (int k = 0; k < 6; ++k) {
        float a;
        if constexpr (BF16) {
          a = bdot(Wb[k][0], X[0], 0.f);
          a = bdot(Wb[k][1], X[1], a);
          a = bdot(Wb[k][2], X[2], a);
          a = bdot(Wb[k][3], X[3], a);
        } else {
          a = dot4f(Wf[k][0], X[0], 0.f);
          a = dot4f(Wf[k][1], X[1], a);
          a = dot4f(Wf[k][2], X[2], a);
          a = dot4f(Wf[k][3], X[3], a);
        }
        d[k] = wredux(a);
      }
      float* hnew = hs4 + (((r) & 3) * NLVL + lvl) * HDIM;
      if (lane == 0) {
        float gi0 = sigmoid_f(d[0] + bi[r0] + bh[r0]);
        float gg0 = tanhf(d[1] + bi[2 * HDIM + r0] + bh[2 * HDIM + r0]);
        float go0 = sigmoid_f(d[2] + bi[3 * HDIM + r0] + bh[3 * HDIM + r0]);
        gstore(hnew + r0, go0 * tanhf(gi0 * gg0));
        float gi1 = sigmoid_f(d[3] + bi[r1] + bh[r1]);
        float gg1 = tanhf(d[4] + bi[2 * HDIM + r1] + bh[2 * HDIM + r1]);
        float go1 = sigmoid_f(d[5] + bi[3 * HDIM + r1] + bh[3 * HDIM + r1]);
        gstore(hnew + r1, go1 * tanhf(gi1 * gg1));
      }
      if (wgl == 0) {   // fe += prec * sum(enc^2)
        float s = fmaf(e0, e0, e1 * e1);
        s = wredux(s);
        if (lane == 0) sred[wave] = s;
        __syncthreads();
        if (threadIdx.x == 0) {
          float tot = 0.f;
#pragma unroll
          for (int k = 0; k < NWAVES; ++k) tot += sred[k];
          fe_local += pr * tot;
        }
      }
    }
    lbar(myarr, mygen, ++bk);
  }

  if (wgl == 0 && threadIdx.x == 0) {
    gstore(ctrlf + C_FEPT(lvl), fe_local);
    asm volatile("s_waitcnt vmcnt(0)" ::: "memory");
    __hip_atomic_fetch_add(ctrl + C_FIN, 1u, __ATOMIC_RELAXED,
                           __HIP_MEMORY_SCOPE_AGENT);
  }
  if (wg == 0 && threadIdx.x == 0) {
    while (uload(ctrl + C_FIN) < (unsigned)NLVL) __builtin_amdgcn_s_sleep(1);
    out[2 * NLVL * HDIM] = gload(ctrlf + C_FEPT(0)) + gload(ctrlf + C_FEPT(1)) +
                           gload(ctrlf + C_FEPT(2)) + gload(ctrlf + C_FEPT(3));
  }
}

extern "C" void kernel_launch(void* const* d_in, const int* in_sizes, int n_in,
                              void* d_out, int out_size, void* d_ws, size_t ws_size,
                              hipStream_t stream) {
  const float* observed = (const float*)d_in[0];
  const float* pw1 = (const float*)d_in[1];
  const float* pb1 = (const float*)d_in[2];
  const float* pw2 = (const float*)d_in[3];
  const float* pb2 = (const float*)d_in[4];
  const float* ew1 = (const float*)d_in[5];
  const float* eb1 = (const float*)d_in[6];
  const float* ew2 = (const float*)d_in[7];
  const float* eb2 = (const float*)d_in[8];
  const float* qw  = (const float*)d_in[9];
  const float* qb  = (const float*)d_in[10];
  const float* wih = (const float*)d_in[11];
  // d_in[12] = whh — unused (h0 == 0 per step)
  const float* bih = (const float*)d_in[13];
  const float* bhh = (const float*)d_in[14];
  float* out = (float*)d_out;
  float* ws  = (float*)d_ws;
  u16* bw = (u16*)((char*)d_ws + (size_t)WS_BF16 * 4);

  const size_t need = (size_t)WS_BF16 * 4 + (size_t)BW_TOTAL * 2;
  const bool use_bf16 = (ws_size >= need);   // ws_size fixed -> same path every call

  hipLaunchKernelGGL(tpn_init, dim3(64), dim3(256), 0, stream, ws);

  if (use_bf16) {
    const int nsq = NLVL * HDIM * HDIM;
    hipLaunchKernelGGL(cvt_sq, dim3(512), dim3(256), 0, stream, pw1, bw + BW_P1, nsq);
    hipLaunchKernelGGL(cvt_sq, dim3(512), dim3(256), 0, stream, pw2, bw + BW_P2, nsq);
    hipLaunchKernelGGL(cvt_sq, dim3(512), dim3(256), 0, stream, ew1, bw + BW_E1, nsq);
    hipLaunchKernelGGL(cvt_sq, dim3(512), dim3(256), 0, stream, ew2, bw + BW_E2, nsq);
    hipLaunchKernelGGL(cvt_ih, dim3(512), dim3(256), 0, stream, wih, bw + BW_IH);
  }

  const u16* bwc = bw;
  void* args[] = { &observed, &pw1, &pb1, &pw2, &pb2, &ew1, &eb1, &ew2, &eb2,
                   &qw, &qb, &wih, &bih, &bhh, &out, &ws, &bwc };
  if (use_bf16) {
    (void)hipLaunchCooperativeKernel((void*)tpn_main_t<true>, dim3(NWG),
                                     dim3(THREADS), args, 0, stream);
  } else {
    (void)hipLaunchCooperativeKernel((void*)tpn_main_t<false>, dim3(NWG),
                                     dim3(THREADS), args, 0, stream);
  }
}